// Round 1
// baseline (433.513 us; speedup 1.0000x reference)
//
#include <hip/hip_runtime.h>
#include <hip/hip_bf16.h>

// CrossAttention: q = q_in@Wq+bq; k = k_v@Wk+bk; v = k_v@Wv+bv
// S = q@k^T * EMBED^-0.5 ; P = softmax(S) ; out = P@v
// B=8, I=J=2048, D=1024. All f32 in/out; internal compute bf16 MFMA.

#define BATCH 8
#define SEQ   2048
#define EMB   1024
#define SCALEF 0.03125f            // 1024^-0.5
#define SC2   0.045084222f         // SCALEF * log2(e)

typedef __attribute__((ext_vector_type(8))) short bf16x8;
typedef __attribute__((ext_vector_type(4))) float f32x4;
typedef __attribute__((ext_vector_type(4))) unsigned short u16x4;
typedef __attribute__((ext_vector_type(8))) unsigned short u16x8;
typedef __attribute__((ext_vector_type(4))) float fl4;

__device__ __forceinline__ unsigned short f2bf(float f) {
    unsigned u = __builtin_bit_cast(unsigned, f);
    unsigned r = u + 0x7fffu + ((u >> 16) & 1u);   // RNE
    return (unsigned short)(r >> 16);
}
__device__ __forceinline__ float bf2f(unsigned short s) {
    return __builtin_bit_cast(float, ((unsigned)s) << 16);
}

// ---------------------------------------------------------------------------
// Kernel 1: projection GEMM.  C[m][n] = sum_k A[m][k]*W[k][n] + bias[n]
// A: f32 [16384][1024] (q_in for proj0, k_v for proj1/2), W: f32 [1024][1024]
// proj0 -> qb bf16 [16384][1024]; proj1 -> kb same; proj2 -> vt bf16 [8][1024][2048]
// Tile 128x128, BK=32, 4 waves (2x2), each wave 64x64.
// ---------------------------------------------------------------------------
#define PLDK 40   // padded K stride (bf16) for BK=32

__global__ __launch_bounds__(256, 2)
void proj_kernel(const float* __restrict__ q_in, const float* __restrict__ k_v,
                 const float* __restrict__ Wq, const float* __restrict__ bq,
                 const float* __restrict__ Wk, const float* __restrict__ bk,
                 const float* __restrict__ Wv, const float* __restrict__ bv,
                 unsigned short* __restrict__ qb, unsigned short* __restrict__ kb,
                 unsigned short* __restrict__ vt)
{
    const int proj = blockIdx.y;
    const float* A; const float* W; const float* bias;
    if (proj == 0)      { A = q_in; W = Wq; bias = bq; }
    else if (proj == 1) { A = k_v;  W = Wk; bias = bk; }
    else                { A = k_v;  W = Wv; bias = bv; }

    const int m0 = (blockIdx.x >> 3) * 128;   // 128 M-tiles
    const int n0 = (blockIdx.x & 7) * 128;    // 8 N-tiles

    __shared__ unsigned short lA[128 * PLDK];
    __shared__ unsigned short lB[128 * PLDK];   // W^T tile: [n][k]

    const int tid = threadIdx.x;
    const int lane = tid & 63;
    const int w = tid >> 6, wr = w >> 1, wc = w & 1;
    const int r = lane & 15, g = lane >> 4;

    const int arow = tid >> 3, akc = tid & 7;   // A staging: row 0..31, k-chunk of 4
    const int bn = tid & 127, bkh = tid >> 7;   // W staging: n 0..127, k-half

    f32x4 acc[4][4];
#pragma unroll
    for (int i = 0; i < 4; i++)
#pragma unroll
        for (int j = 0; j < 4; j++) acc[i][j] = (f32x4)0.0f;

    for (int k0 = 0; k0 < EMB; k0 += 32) {
        __syncthreads();
        // stage A tile (f32 -> bf16)
#pragma unroll
        for (int it = 0; it < 4; it++) {
            const int row = arow + it * 32;
            fl4 a4 = *(const fl4*)&A[(size_t)(m0 + row) * EMB + k0 + akc * 4];
            u16x4 u;
            u[0] = f2bf(a4[0]); u[1] = f2bf(a4[1]); u[2] = f2bf(a4[2]); u[3] = f2bf(a4[3]);
            *(u16x4*)&lA[row * PLDK + akc * 4] = u;
        }
        // stage W^T tile: lB[n][k] (scalar f32 loads, coalesced along n)
#pragma unroll
        for (int it = 0; it < 4; it++) {
            const int ks = bkh * 16 + it * 4;
            u16x4 u;
#pragma unroll
            for (int q = 0; q < 4; q++)
                u[q] = f2bf(W[(size_t)(k0 + ks + q) * EMB + n0 + bn]);
            *(u16x4*)&lB[bn * PLDK + ks] = u;
        }
        __syncthreads();

        bf16x8 af[4], bfv[4];
#pragma unroll
        for (int m = 0; m < 4; m++)
            af[m] = *(bf16x8*)&lA[(wr * 64 + m * 16 + r) * PLDK + g * 8];
#pragma unroll
        for (int n = 0; n < 4; n++)
            bfv[n] = *(bf16x8*)&lB[(wc * 64 + n * 16 + r) * PLDK + g * 8];
#pragma unroll
        for (int m = 0; m < 4; m++)
#pragma unroll
            for (int n = 0; n < 4; n++)
                acc[m][n] = __builtin_amdgcn_mfma_f32_16x16x32_bf16(af[m], bfv[n], acc[m][n], 0, 0, 0);
    }

    // epilogue: + bias, convert, store
#pragma unroll
    for (int n = 0; n < 4; n++) {
        const int col = n0 + wc * 64 + n * 16 + r;
        const float bb = bias[col];
#pragma unroll
        for (int m = 0; m < 4; m++) {
            const int rowb = m0 + wr * 64 + m * 16 + g * 4;
            if (proj == 2) {
                const int bidx = rowb >> 11;
                const int j = rowb & 2047;
                u16x4 u;
#pragma unroll
                for (int i = 0; i < 4; i++) u[i] = f2bf(acc[m][n][i] + bb);
                *(u16x4*)&vt[((size_t)bidx * EMB + col) * SEQ + j] = u;
            } else {
                unsigned short* o = (proj == 0) ? qb : kb;
#pragma unroll
                for (int i = 0; i < 4; i++)
                    o[(size_t)(rowb + i) * EMB + col] = f2bf(acc[m][n][i] + bb);
            }
        }
    }
}

// ---------------------------------------------------------------------------
// Kernel 2: S-tile = qb @ kb^T, P = exp2(S * scale * log2e) stored bf16.
// Both operands row-major with contiguous K (=d). Tile 128x128, BK=64.
// ---------------------------------------------------------------------------
#define QLDK 72   // padded K stride (bf16) for BK=64

__global__ __launch_bounds__(256, 2)
void qk_kernel(const unsigned short* __restrict__ qb,
               const unsigned short* __restrict__ kb,
               unsigned short* __restrict__ P)
{
    const int b = blockIdx.z;
    const int m0 = blockIdx.x * 128;   // i
    const int n0 = blockIdx.y * 128;   // j
    const unsigned short* Aq = qb + (size_t)b * SEQ * EMB;
    const unsigned short* Bk = kb + (size_t)b * SEQ * EMB;

    __shared__ unsigned short lA[128 * QLDK];
    __shared__ unsigned short lB[128 * QLDK];

    const int tid = threadIdx.x, lane = tid & 63;
    const int w = tid >> 6, wr = w >> 1, wc = w & 1;
    const int r = lane & 15, g = lane >> 4;
    const int srow = tid >> 3, skc = tid & 7;

    f32x4 acc[4][4];
#pragma unroll
    for (int i = 0; i < 4; i++)
#pragma unroll
        for (int j = 0; j < 4; j++) acc[i][j] = (f32x4)0.0f;

    for (int k0 = 0; k0 < EMB; k0 += 64) {
        __syncthreads();
#pragma unroll
        for (int it = 0; it < 4; it++) {
            const int row = srow + it * 32;
            *(u16x8*)&lA[row * QLDK + skc * 8] =
                *(const u16x8*)&Aq[(size_t)(m0 + row) * EMB + k0 + skc * 8];
            *(u16x8*)&lB[row * QLDK + skc * 8] =
                *(const u16x8*)&Bk[(size_t)(n0 + row) * EMB + k0 + skc * 8];
        }
        __syncthreads();
#pragma unroll
        for (int kk = 0; kk < 2; kk++) {
            bf16x8 af[4], bfv[4];
#pragma unroll
            for (int m = 0; m < 4; m++)
                af[m] = *(bf16x8*)&lA[(wr * 64 + m * 16 + r) * QLDK + kk * 32 + g * 8];
#pragma unroll
            for (int n = 0; n < 4; n++)
                bfv[n] = *(bf16x8*)&lB[(wc * 64 + n * 16 + r) * QLDK + kk * 32 + g * 8];
#pragma unroll
            for (int m = 0; m < 4; m++)
#pragma unroll
                for (int n = 0; n < 4; n++)
                    acc[m][n] = __builtin_amdgcn_mfma_f32_16x16x32_bf16(af[m], bfv[n], acc[m][n], 0, 0, 0);
        }
    }

    unsigned short* Pb = P + (size_t)b * SEQ * SEQ;
#pragma unroll
    for (int m = 0; m < 4; m++) {
        const int ib = m0 + wr * 64 + m * 16 + g * 4;
#pragma unroll
        for (int n = 0; n < 4; n++) {
            const int j = n0 + wc * 64 + n * 16 + r;
#pragma unroll
            for (int i = 0; i < 4; i++) {
                const float p = exp2f(acc[m][n][i] * SC2);   // no max-sub: |S|<~6
                Pb[(size_t)(ib + i) * SEQ + j] = f2bf(p);
            }
        }
    }
}

// ---------------------------------------------------------------------------
// Kernel 3: rowsum of P (deterministic softmax denominator). 1 wave per row.
// ---------------------------------------------------------------------------
__global__ __launch_bounds__(256)
void rowsum_kernel(const unsigned short* __restrict__ P, float* __restrict__ rs)
{
    const int row = blockIdx.x * 4 + (threadIdx.x >> 6);
    const int lane = threadIdx.x & 63;
    const unsigned short* p = P + (size_t)row * SEQ;
    float s = 0.f;
#pragma unroll
    for (int it = 0; it < 4; it++) {
        u16x8 u = *(const u16x8*)&p[it * 512 + lane * 8];
#pragma unroll
        for (int q = 0; q < 8; q++) s += bf2f(u[q]);
    }
#pragma unroll
    for (int off = 32; off > 0; off >>= 1) s += __shfl_down(s, off);
    if (lane == 0) rs[row] = s;
}

// ---------------------------------------------------------------------------
// Kernel 4: out = (P @ v) / rowsum.  A = P [i][j] (K=j contig),
// B = vt [d][j] (K=j contig). Tile 128x128, BK=64, K=2048.
// ---------------------------------------------------------------------------
__global__ __launch_bounds__(256, 2)
void pv_kernel(const unsigned short* __restrict__ P,
               const unsigned short* __restrict__ vt,
               const float* __restrict__ rs,
               float* __restrict__ out)
{
    const int b = blockIdx.z;
    const int m0 = blockIdx.x * 128;   // i
    const int n0 = blockIdx.y * 128;   // d
    const unsigned short* Ap = P  + (size_t)b * SEQ * SEQ;
    const unsigned short* Bv = vt + (size_t)b * EMB * SEQ;

    __shared__ unsigned short lA[128 * QLDK];
    __shared__ unsigned short lB[128 * QLDK];

    const int tid = threadIdx.x, lane = tid & 63;
    const int w = tid >> 6, wr = w >> 1, wc = w & 1;
    const int r = lane & 15, g = lane >> 4;
    const int srow = tid >> 3, skc = tid & 7;

    f32x4 acc[4][4];
#pragma unroll
    for (int i = 0; i < 4; i++)
#pragma unroll
        for (int j = 0; j < 4; j++) acc[i][j] = (f32x4)0.0f;

    for (int k0 = 0; k0 < SEQ; k0 += 64) {
        __syncthreads();
#pragma unroll
        for (int it = 0; it < 4; it++) {
            const int row = srow + it * 32;
            *(u16x8*)&lA[row * QLDK + skc * 8] =
                *(const u16x8*)&Ap[(size_t)(m0 + row) * SEQ + k0 + skc * 8];
            *(u16x8*)&lB[row * QLDK + skc * 8] =
                *(const u16x8*)&Bv[(size_t)(n0 + row) * SEQ + k0 + skc * 8];
        }
        __syncthreads();
#pragma unroll
        for (int kk = 0; kk < 2; kk++) {
            bf16x8 af[4], bfv[4];
#pragma unroll
            for (int m = 0; m < 4; m++)
                af[m] = *(bf16x8*)&lA[(wr * 64 + m * 16 + r) * QLDK + kk * 32 + g * 8];
#pragma unroll
            for (int n = 0; n < 4; n++)
                bfv[n] = *(bf16x8*)&lB[(wc * 64 + n * 16 + r) * QLDK + kk * 32 + g * 8];
#pragma unroll
            for (int m = 0; m < 4; m++)
#pragma unroll
                for (int n = 0; n < 4; n++)
                    acc[m][n] = __builtin_amdgcn_mfma_f32_16x16x32_bf16(af[m], bfv[n], acc[m][n], 0, 0, 0);
        }
    }

    float* ob = out + (size_t)b * SEQ * EMB;
    const float* rsb = rs + (size_t)b * SEQ;
#pragma unroll
    for (int m = 0; m < 4; m++) {
        const int ib = m0 + wr * 64 + m * 16 + g * 4;
#pragma unroll
        for (int i = 0; i < 4; i++) {
            const float inv = 1.0f / rsb[ib + i];
#pragma unroll
            for (int n = 0; n < 4; n++) {
                const int d = n0 + wc * 64 + n * 16 + r;
                ob[(size_t)(ib + i) * EMB + d] = acc[m][n][i] * inv;
            }
        }
    }
}

// ---------------------------------------------------------------------------
extern "C" void kernel_launch(void* const* d_in, const int* in_sizes, int n_in,
                              void* d_out, int out_size, void* d_ws, size_t ws_size,
                              hipStream_t stream)
{
    const float* q_in = (const float*)d_in[0];
    const float* k_v  = (const float*)d_in[1];
    const float* Wq   = (const float*)d_in[2];
    const float* bq   = (const float*)d_in[3];
    const float* Wk   = (const float*)d_in[4];
    const float* bk   = (const float*)d_in[5];
    const float* Wv   = (const float*)d_in[6];
    const float* bv   = (const float*)d_in[7];
    float* out = (float*)d_out;

    // workspace layout (bytes):
    //   qb  bf16 [8][2048][1024]  @ 0         (32 MB)
    //   kb  bf16 [8][2048][1024]  @ 32 MB
    //   vt  bf16 [8][1024][2048]  @ 64 MB     (v transposed per batch)
    //   P   bf16 [8][2048][2048]  @ 96 MB     (64 MB)
    //   rs  f32  [8][2048]        @ 160 MB
    char* ws = (char*)d_ws;
    unsigned short* qb = (unsigned short*)(ws);
    unsigned short* kb = (unsigned short*)(ws + (size_t)33554432);
    unsigned short* vt = (unsigned short*)(ws + (size_t)67108864);
    unsigned short* P  = (unsigned short*)(ws + (size_t)100663296);
    float*          rs = (float*)(ws + (size_t)167772160);

    proj_kernel<<<dim3(1024, 3), 256, 0, stream>>>(q_in, k_v, Wq, bq, Wk, bk, Wv, bv,
                                                   qb, kb, vt);
    qk_kernel<<<dim3(16, 16, BATCH), 256, 0, stream>>>(qb, kb, P);
    rowsum_kernel<<<dim3(4096), 256, 0, stream>>>(P, rs);
    pv_kernel<<<dim3(16, 8, BATCH), 256, 0, stream>>>(P, vt, rs, out);
}

// Round 2
// 353.016 us; speedup vs baseline: 1.2280x; 1.2280x over previous
//
#include <hip/hip_runtime.h>
#include <hip/hip_bf16.h>

// CrossAttention: q = q_in@Wq+bq; k = k_v@Wk+bk; v = k_v@Wv+bv
// S = q@k^T * EMBED^-0.5 ; P = softmax(S) ; out = P@v
// B=8, I=J=2048, D=1024. All f32 in/out; internal compute bf16 MFMA.

#define BATCH 8
#define SEQ   2048
#define EMB   1024
#define SC2   0.045084222f         // EMB^-0.5 * log2(e)

typedef __attribute__((ext_vector_type(8))) short bf16x8;
typedef __attribute__((ext_vector_type(4))) float f32x4;
typedef __attribute__((ext_vector_type(4))) unsigned short u16x4;
typedef __attribute__((ext_vector_type(8))) unsigned short u16x8;
typedef __attribute__((ext_vector_type(4))) float fl4;

__device__ __forceinline__ unsigned short f2bf(float f) {
    unsigned u = __builtin_bit_cast(unsigned, f);
    unsigned r = u + 0x7fffu + ((u >> 16) & 1u);   // RNE
    return (unsigned short)(r >> 16);
}
__device__ __forceinline__ float bf2f(unsigned short s) {
    return __builtin_bit_cast(float, ((unsigned)s) << 16);
}
__device__ __forceinline__ void gload16(const unsigned short* g, unsigned short* l) {
    __builtin_amdgcn_global_load_lds(
        (const __attribute__((address_space(1))) void*)g,
        (__attribute__((address_space(3))) void*)l, 16, 0, 0);
}

// ---------------------------------------------------------------------------
// Convert f32 inputs -> bf16 (q_in -> qbin, k_v -> kvbin)
// ---------------------------------------------------------------------------
__global__ __launch_bounds__(256)
void convert_in(const float* __restrict__ q_in, const float* __restrict__ k_v,
                unsigned short* __restrict__ qbin, unsigned short* __restrict__ kvbin)
{
    const size_t N = (size_t)BATCH * SEQ * EMB;   // 16777216
    size_t idx = ((size_t)blockIdx.x * 256 + threadIdx.x) * 8;
    const size_t stride = (size_t)gridDim.x * 256 * 8;
    for (; idx < N; idx += stride) {
        fl4 a0 = *(const fl4*)&q_in[idx];
        fl4 a1 = *(const fl4*)&q_in[idx + 4];
        fl4 b0 = *(const fl4*)&k_v[idx];
        fl4 b1 = *(const fl4*)&k_v[idx + 4];
        u16x8 ua, ub;
#pragma unroll
        for (int i = 0; i < 4; i++) {
            ua[i] = f2bf(a0[i]); ua[i + 4] = f2bf(a1[i]);
            ub[i] = f2bf(b0[i]); ub[i + 4] = f2bf(b1[i]);
        }
        *(u16x8*)&qbin[idx] = ua;
        *(u16x8*)&kvbin[idx] = ub;
    }
}

// ---------------------------------------------------------------------------
// Convert + transpose W [k][n] f32 -> Wt [n][k] bf16 (3 weights concatenated)
// ---------------------------------------------------------------------------
__global__ __launch_bounds__(256)
void convert_w(const float* __restrict__ Wq, const float* __restrict__ Wk,
               const float* __restrict__ Wv, unsigned short* __restrict__ Wt)
{
    const int wsel = blockIdx.y;
    const float* W = (wsel == 0) ? Wq : (wsel == 1) ? Wk : Wv;
    unsigned short* O = Wt + (size_t)wsel * EMB * EMB;
    const int k0 = (blockIdx.x >> 4) * 64;
    const int n0 = (blockIdx.x & 15) * 64;
    __shared__ unsigned short l[64 * 65];
    const int tid = threadIdx.x;
#pragma unroll
    for (int it = 0; it < 16; it++) {
        const int lin = it * 256 + tid;
        const int k = lin >> 6, n = lin & 63;
        l[n * 65 + k] = f2bf(W[(size_t)(k0 + k) * EMB + n0 + n]);
    }
    __syncthreads();
#pragma unroll
    for (int it = 0; it < 16; it++) {
        const int lin = it * 256 + tid;
        const int n = lin >> 6, k = lin & 63;
        O[(size_t)(n0 + n) * EMB + k0 + k] = l[n * 65 + k];
    }
}

// ---------------------------------------------------------------------------
// proj_q: O = X @ Wt^T + bias (all bf16, K-contiguous both operands)
// m97 structure: 128x128 tile, BK=64, global_load_lds(16B), linear LDS.
// ---------------------------------------------------------------------------
__global__ __launch_bounds__(256, 2)
void proj_q_kernel(const unsigned short* __restrict__ X,
                   const unsigned short* __restrict__ Wt,
                   const float* __restrict__ bias,
                   unsigned short* __restrict__ O)
{
    const int bid = blockIdx.x;
    const int mt = ((bid >> 6) << 3) | (bid & 7);   // XCD-grouped M-tiles
    const int nt = (bid >> 3) & 7;
    const int m0 = mt * 128, n0 = nt * 128;

    __shared__ unsigned short lA[128 * 64];
    __shared__ unsigned short lB[128 * 64];

    const int tid = threadIdx.x, lane = tid & 63;
    const int w = tid >> 6, wr = w >> 1, wc = w & 1;
    const int r = lane & 15, g = lane >> 4;
    const int srow = lane >> 3, scol = lane & 7;

    f32x4 acc[4][4];
#pragma unroll
    for (int i = 0; i < 4; i++)
#pragma unroll
        for (int j = 0; j < 4; j++) acc[i][j] = (f32x4)0.0f;

    for (int k0 = 0; k0 < EMB; k0 += 64) {
        __syncthreads();
#pragma unroll
        for (int i = 0; i < 4; i++) {
            const int c = w * 4 + i;           // chunk of 8 rows
            const int row = c * 8 + srow;
            gload16(&X[(size_t)(m0 + row) * EMB + k0 + scol * 8], &lA[c * 512]);
            gload16(&Wt[(size_t)(n0 + row) * EMB + k0 + scol * 8], &lB[c * 512]);
        }
        __syncthreads();
#pragma unroll
        for (int kk = 0; kk < 2; kk++) {
            bf16x8 af[4], bf[4];
#pragma unroll
            for (int m = 0; m < 4; m++)
                af[m] = *(bf16x8*)&lA[(wr * 64 + m * 16 + r) * 64 + kk * 32 + g * 8];
#pragma unroll
            for (int n = 0; n < 4; n++)
                bf[n] = *(bf16x8*)&lB[(wc * 64 + n * 16 + r) * 64 + kk * 32 + g * 8];
#pragma unroll
            for (int m = 0; m < 4; m++)
#pragma unroll
                for (int n = 0; n < 4; n++)
                    acc[m][n] = __builtin_amdgcn_mfma_f32_16x16x32_bf16(af[m], bf[n], acc[m][n], 0, 0, 0);
        }
    }

#pragma unroll
    for (int n = 0; n < 4; n++) {
        const int col = n0 + wc * 64 + n * 16 + r;
        const float bb = bias[col];
#pragma unroll
        for (int m = 0; m < 4; m++) {
            const int rowb = m0 + wr * 64 + m * 16 + g * 4;
#pragma unroll
            for (int i = 0; i < 4; i++)
                O[(size_t)(rowb + i) * EMB + col] = f2bf(acc[m][n][i] + bb);
        }
    }
}

// ---------------------------------------------------------------------------
// proj_kv: k = X@Wkt^T+bk -> kb [m][d]; v = X@Wvt^T+bv -> vt [b][d][j]
// Shares the A (k_v) staging between both outputs.
// ---------------------------------------------------------------------------
__global__ __launch_bounds__(256, 2)
void proj_kv_kernel(const unsigned short* __restrict__ X,
                    const unsigned short* __restrict__ Wkt,
                    const unsigned short* __restrict__ Wvt,
                    const float* __restrict__ bk, const float* __restrict__ bv,
                    unsigned short* __restrict__ kb, unsigned short* __restrict__ vt)
{
    const int bid = blockIdx.x;
    const int mt = ((bid >> 6) << 3) | (bid & 7);
    const int nt = (bid >> 3) & 7;
    const int m0 = mt * 128, n0 = nt * 128;

    __shared__ unsigned short lA[128 * 64];
    __shared__ unsigned short lBk[128 * 64];
    __shared__ unsigned short lBv[128 * 64];

    const int tid = threadIdx.x, lane = tid & 63;
    const int w = tid >> 6, wr = w >> 1, wc = w & 1;
    const int r = lane & 15, g = lane >> 4;
    const int srow = lane >> 3, scol = lane & 7;

    f32x4 acck[4][4], accv[4][4];
#pragma unroll
    for (int i = 0; i < 4; i++)
#pragma unroll
        for (int j = 0; j < 4; j++) { acck[i][j] = (f32x4)0.0f; accv[i][j] = (f32x4)0.0f; }

    for (int k0 = 0; k0 < EMB; k0 += 64) {
        __syncthreads();
#pragma unroll
        for (int i = 0; i < 4; i++) {
            const int c = w * 4 + i;
            const int row = c * 8 + srow;
            const size_t goff = (size_t)row * EMB + k0 + scol * 8;
            gload16(&X[(size_t)m0 * EMB + goff], &lA[c * 512]);
            gload16(&Wkt[(size_t)n0 * EMB + goff], &lBk[c * 512]);
            gload16(&Wvt[(size_t)n0 * EMB + goff], &lBv[c * 512]);
        }
        __syncthreads();
#pragma unroll
        for (int kk = 0; kk < 2; kk++) {
            bf16x8 af[4], bfk[4], bfv[4];
#pragma unroll
            for (int m = 0; m < 4; m++)
                af[m] = *(bf16x8*)&lA[(wr * 64 + m * 16 + r) * 64 + kk * 32 + g * 8];
#pragma unroll
            for (int n = 0; n < 4; n++) {
                bfk[n] = *(bf16x8*)&lBk[(wc * 64 + n * 16 + r) * 64 + kk * 32 + g * 8];
                bfv[n] = *(bf16x8*)&lBv[(wc * 64 + n * 16 + r) * 64 + kk * 32 + g * 8];
            }
#pragma unroll
            for (int m = 0; m < 4; m++)
#pragma unroll
                for (int n = 0; n < 4; n++) {
                    acck[m][n] = __builtin_amdgcn_mfma_f32_16x16x32_bf16(af[m], bfk[n], acck[m][n], 0, 0, 0);
                    accv[m][n] = __builtin_amdgcn_mfma_f32_16x16x32_bf16(af[m], bfv[n], accv[m][n], 0, 0, 0);
                }
        }
    }

    const int b = m0 >> 11;              // batch of this 128-row tile
    const int j0 = m0 & 2047;
#pragma unroll
    for (int n = 0; n < 4; n++) {
        const int col = n0 + wc * 64 + n * 16 + r;
        const float bbk = bk[col];
        const float bbv = bv[col];
#pragma unroll
        for (int m = 0; m < 4; m++) {
            const int rowb = m0 + wr * 64 + m * 16 + g * 4;
#pragma unroll
            for (int i = 0; i < 4; i++)
                kb[(size_t)(rowb + i) * EMB + col] = f2bf(acck[m][n][i] + bbk);
            // v transposed: vt[b][d=col][j]
            const int j = j0 + wr * 64 + m * 16 + g * 4;
            u16x4 u;
#pragma unroll
            for (int i = 0; i < 4; i++) u[i] = f2bf(accv[m][n][i] + bbv);
            *(u16x4*)&vt[((size_t)b * EMB + col) * SEQ + j] = u;
        }
    }
}

// ---------------------------------------------------------------------------
// Kernel 2: S-tile = qb @ kb^T, P = exp2(S * scale * log2e) stored bf16.
// ---------------------------------------------------------------------------
#define QLDK 72   // padded K stride (bf16) for BK=64

__global__ __launch_bounds__(256, 2)
void qk_kernel(const unsigned short* __restrict__ qb,
               const unsigned short* __restrict__ kb,
               unsigned short* __restrict__ P)
{
    const int b = blockIdx.z;
    const int m0 = blockIdx.x * 128;   // i
    const int n0 = blockIdx.y * 128;   // j
    const unsigned short* Aq = qb + (size_t)b * SEQ * EMB;
    const unsigned short* Bk = kb + (size_t)b * SEQ * EMB;

    __shared__ unsigned short lA[128 * QLDK];
    __shared__ unsigned short lB[128 * QLDK];

    const int tid = threadIdx.x, lane = tid & 63;
    const int w = tid >> 6, wr = w >> 1, wc = w & 1;
    const int r = lane & 15, g = lane >> 4;
    const int srow = tid >> 3, skc = tid & 7;

    f32x4 acc[4][4];
#pragma unroll
    for (int i = 0; i < 4; i++)
#pragma unroll
        for (int j = 0; j < 4; j++) acc[i][j] = (f32x4)0.0f;

    for (int k0 = 0; k0 < EMB; k0 += 64) {
        __syncthreads();
#pragma unroll
        for (int it = 0; it < 4; it++) {
            const int row = srow + it * 32;
            *(u16x8*)&lA[row * QLDK + skc * 8] =
                *(const u16x8*)&Aq[(size_t)(m0 + row) * EMB + k0 + skc * 8];
            *(u16x8*)&lB[row * QLDK + skc * 8] =
                *(const u16x8*)&Bk[(size_t)(n0 + row) * EMB + k0 + skc * 8];
        }
        __syncthreads();
#pragma unroll
        for (int kk = 0; kk < 2; kk++) {
            bf16x8 af[4], bfv[4];
#pragma unroll
            for (int m = 0; m < 4; m++)
                af[m] = *(bf16x8*)&lA[(wr * 64 + m * 16 + r) * QLDK + kk * 32 + g * 8];
#pragma unroll
            for (int n = 0; n < 4; n++)
                bfv[n] = *(bf16x8*)&lB[(wc * 64 + n * 16 + r) * QLDK + kk * 32 + g * 8];
#pragma unroll
            for (int m = 0; m < 4; m++)
#pragma unroll
                for (int n = 0; n < 4; n++)
                    acc[m][n] = __builtin_amdgcn_mfma_f32_16x16x32_bf16(af[m], bfv[n], acc[m][n], 0, 0, 0);
        }
    }

    unsigned short* Pb = P + (size_t)b * SEQ * SEQ;
#pragma unroll
    for (int m = 0; m < 4; m++) {
        const int ib = m0 + wr * 64 + m * 16 + g * 4;
#pragma unroll
        for (int n = 0; n < 4; n++) {
            const int j = n0 + wc * 64 + n * 16 + r;
#pragma unroll
            for (int i = 0; i < 4; i++) {
                const float p = exp2f(acc[m][n][i] * SC2);   // no max-sub: |S|<~6
                Pb[(size_t)(ib + i) * SEQ + j] = f2bf(p);
            }
        }
    }
}

// ---------------------------------------------------------------------------
// Kernel 3: rowsum of P (deterministic softmax denominator).
// ---------------------------------------------------------------------------
__global__ __launch_bounds__(256)
void rowsum_kernel(const unsigned short* __restrict__ P, float* __restrict__ rs)
{
    const int row = blockIdx.x * 4 + (threadIdx.x >> 6);
    const int lane = threadIdx.x & 63;
    const unsigned short* p = P + (size_t)row * SEQ;
    float s = 0.f;
#pragma unroll
    for (int it = 0; it < 4; it++) {
        u16x8 u = *(const u16x8*)&p[it * 512 + lane * 8];
#pragma unroll
        for (int q = 0; q < 8; q++) s += bf2f(u[q]);
    }
#pragma unroll
    for (int off = 32; off > 0; off >>= 1) s += __shfl_down(s, off);
    if (lane == 0) rs[row] = s;
}

// ---------------------------------------------------------------------------
// Kernel 4: out = (P @ v) / rowsum.
// ---------------------------------------------------------------------------
__global__ __launch_bounds__(256, 2)
void pv_kernel(const unsigned short* __restrict__ P,
               const unsigned short* __restrict__ vt,
               const float* __restrict__ rs,
               float* __restrict__ out)
{
    const int b = blockIdx.z;
    const int m0 = blockIdx.x * 128;   // i
    const int n0 = blockIdx.y * 128;   // d
    const unsigned short* Ap = P  + (size_t)b * SEQ * SEQ;
    const unsigned short* Bv = vt + (size_t)b * EMB * SEQ;

    __shared__ unsigned short lA[128 * QLDK];
    __shared__ unsigned short lB[128 * QLDK];

    const int tid = threadIdx.x, lane = tid & 63;
    const int w = tid >> 6, wr = w >> 1, wc = w & 1;
    const int r = lane & 15, g = lane >> 4;
    const int srow = tid >> 3, skc = tid & 7;

    f32x4 acc[4][4];
#pragma unroll
    for (int i = 0; i < 4; i++)
#pragma unroll
        for (int j = 0; j < 4; j++) acc[i][j] = (f32x4)0.0f;

    for (int k0 = 0; k0 < SEQ; k0 += 64) {
        __syncthreads();
#pragma unroll
        for (int it = 0; it < 4; it++) {
            const int row = srow + it * 32;
            *(u16x8*)&lA[row * QLDK + skc * 8] =
                *(const u16x8*)&Ap[(size_t)(m0 + row) * SEQ + k0 + skc * 8];
            *(u16x8*)&lB[row * QLDK + skc * 8] =
                *(const u16x8*)&Bv[(size_t)(n0 + row) * SEQ + k0 + skc * 8];
        }
        __syncthreads();
#pragma unroll
        for (int kk = 0; kk < 2; kk++) {
            bf16x8 af[4], bfv[4];
#pragma unroll
            for (int m = 0; m < 4; m++)
                af[m] = *(bf16x8*)&lA[(wr * 64 + m * 16 + r) * QLDK + kk * 32 + g * 8];
#pragma unroll
            for (int n = 0; n < 4; n++)
                bfv[n] = *(bf16x8*)&lB[(wc * 64 + n * 16 + r) * QLDK + kk * 32 + g * 8];
#pragma unroll
            for (int m = 0; m < 4; m++)
#pragma unroll
                for (int n = 0; n < 4; n++)
                    acc[m][n] = __builtin_amdgcn_mfma_f32_16x16x32_bf16(af[m], bfv[n], acc[m][n], 0, 0, 0);
        }
    }

    float* ob = out + (size_t)b * SEQ * EMB;
    const float* rsb = rs + (size_t)b * SEQ;
#pragma unroll
    for (int m = 0; m < 4; m++) {
        const int ib = m0 + wr * 64 + m * 16 + g * 4;
#pragma unroll
        for (int i = 0; i < 4; i++) {
            const float inv = 1.0f / rsb[ib + i];
#pragma unroll
            for (int n = 0; n < 4; n++) {
                const int d = n0 + wc * 64 + n * 16 + r;
                ob[(size_t)(ib + i) * EMB + d] = acc[m][n][i] * inv;
            }
        }
    }
}

// ---------------------------------------------------------------------------
extern "C" void kernel_launch(void* const* d_in, const int* in_sizes, int n_in,
                              void* d_out, int out_size, void* d_ws, size_t ws_size,
                              hipStream_t stream)
{
    const float* q_in = (const float*)d_in[0];
    const float* k_v  = (const float*)d_in[1];
    const float* Wq   = (const float*)d_in[2];
    const float* bq   = (const float*)d_in[3];
    const float* Wk   = (const float*)d_in[4];
    const float* bk   = (const float*)d_in[5];
    const float* Wv   = (const float*)d_in[6];
    const float* bv   = (const float*)d_in[7];
    float* out = (float*)d_out;

    // workspace layout (bytes, MB = 1048576):
    //   qbin  bf16 [8][2048][1024] @ 0      (32 MB)  -- dead after proj_q
    //   kvbin bf16 [8][2048][1024] @ 32 MB  (32 MB)  -- dead after proj_kv
    //   P     bf16 [8][2048][2048] @ 0      (64 MB)  -- aliases qbin+kvbin
    //   qb    bf16                 @ 64 MB  (32 MB)
    //   kb    bf16                 @ 96 MB  (32 MB)
    //   vt    bf16 [8][1024][2048] @ 128 MB (32 MB)
    //   Wt    bf16 3x[1024][1024]  @ 160 MB (6 MB)
    //   rs    f32  [8][2048]       @ 166 MB
    char* ws = (char*)d_ws;
    unsigned short* qbin = (unsigned short*)(ws);
    unsigned short* kvbin= (unsigned short*)(ws + (size_t)33554432);
    unsigned short* P    = (unsigned short*)(ws);
    unsigned short* qb   = (unsigned short*)(ws + (size_t)67108864);
    unsigned short* kb   = (unsigned short*)(ws + (size_t)100663296);
    unsigned short* vt   = (unsigned short*)(ws + (size_t)134217728);
    unsigned short* Wt   = (unsigned short*)(ws + (size_t)167772160);
    float*          rs   = (float*)(ws + (size_t)174063616);

    convert_in<<<4096, 256, 0, stream>>>(q_in, k_v, qbin, kvbin);
    convert_w<<<dim3(256, 3), 256, 0, stream>>>(Wq, Wk, Wv, Wt);
    proj_q_kernel<<<1024, 256, 0, stream>>>(qbin, Wt, bq, qb);
    proj_kv_kernel<<<1024, 256, 0, stream>>>(kvbin, Wt + (size_t)EMB * EMB,
                                             Wt + (size_t)2 * EMB * EMB, bk, bv, kb, vt);
    qk_kernel<<<dim3(16, 16, BATCH), 256, 0, stream>>>(qb, kb, P);
    rowsum_kernel<<<dim3(4096), 256, 0, stream>>>(P, rs);
    pv_kernel<<<dim3(16, 8, BATCH), 256, 0, stream>>>(P, vt, rs, out);
}